// Round 3
// baseline (704.384 us; speedup 1.0000x reference)
//
#include <hip/hip_runtime.h>

// B=2, T=2048, E=1024, H=8, D=512, HD=4096. bf16 MFMA internally.

#define DEV __device__ __forceinline__

using bf16x8  = __attribute__((ext_vector_type(8))) short;
using floatx4 = __attribute__((ext_vector_type(4))) float;

#define MFMA16(a, b, c) __builtin_amdgcn_mfma_f32_16x16x32_bf16((a), (b), (c), 0, 0, 0)

DEV unsigned short f2bf(float f) {
  union { float f; unsigned int u; } c; c.f = f;
  unsigned int u = c.u + 0x7FFFu + ((c.u >> 16) & 1u);
  return (unsigned short)(u >> 16);
}
DEV float bf2f(unsigned short h) {
  union { unsigned int u; float f; } c; c.u = ((unsigned int)h) << 16;
  return c.f;
}

// async global->LDS, 16B per lane. LDS dest = wave-uniform base + lane*16.
DEV void ldsld16(const unsigned short* g, unsigned short* l) {
  __builtin_amdgcn_global_load_lds(
      (__attribute__((address_space(1))) void*)(g),
      (__attribute__((address_space(3))) void*)(l), 16, 0, 0);
}

// ---------------- fused cast fp32 -> bf16 for all 5 tensors ----------------
__global__ void cast5_k(const float* __restrict__ x,  const float* __restrict__ wq,
                        const float* __restrict__ wk, const float* __restrict__ wv,
                        const float* __restrict__ wo,
                        unsigned short* __restrict__ xb,  unsigned short* __restrict__ wqb,
                        unsigned short* __restrict__ wkb, unsigned short* __restrict__ wvb,
                        unsigned short* __restrict__ wob) {
  const float* s; unsigned short* d;
  switch (blockIdx.y) {
    case 0: s = x;  d = xb;  break;
    case 1: s = wq; d = wqb; break;
    case 2: s = wk; d = wkb; break;
    case 3: s = wv; d = wvb; break;
    default: s = wo; d = wob; break;
  }
  int i = blockIdx.x * 256 + threadIdx.x;
  float4 v = ((const float4*)s)[i];
  uint2 o;
  o.x = (unsigned int)f2bf(v.x) | ((unsigned int)f2bf(v.y) << 16);
  o.y = (unsigned int)f2bf(v.z) | ((unsigned int)f2bf(v.w) << 16);
  ((uint2*)d)[i] = o;
}

// ---------------- QKV projection GEMM ----------------
// Q,K -> [B,H,T,D]. V -> slab layout [BH][T/32][D][32] (coalesced flash staging).
__global__ __launch_bounds__(256) void qkv_gemm(
    const unsigned short* __restrict__ X,
    const unsigned short* __restrict__ Wq, const unsigned short* __restrict__ Wk,
    const unsigned short* __restrict__ Wv,
    unsigned short* __restrict__ Qo, unsigned short* __restrict__ Ko, unsigned short* __restrict__ Vo) {
  __shared__ __align__(16) unsigned short As[128 * 32];
  __shared__ __align__(16) unsigned short Bs[128 * 32];
  const int tid = threadIdx.x;
  const int wave = tid >> 6, lane = tid & 63, quad = lane >> 4, l16 = lane & 15;
  const int m0 = blockIdx.x * 128, n0 = blockIdx.y * 128;
  const int z = blockIdx.z;
  const unsigned short* W = (z == 0) ? Wq : (z == 1) ? Wk : Wv;
  const int wm = (wave >> 1) * 64, wn = (wave & 1) * 64;
  floatx4 acc[4][4];
#pragma unroll
  for (int i = 0; i < 4; ++i)
#pragma unroll
    for (int j = 0; j < 4; ++j) acc[i][j] = (floatx4){0.f, 0.f, 0.f, 0.f};

  const int r0 = wave * 32;
  const int lrow = lane >> 2, lchunk = (lane & 3) * 8;
  for (int k0 = 0; k0 < 1024; k0 += 32) {
    const unsigned short* ga = X + (size_t)(m0 + r0 + lrow) * 1024 + k0 + lchunk;
    const unsigned short* gb = W + (size_t)(n0 + r0 + lrow) * 1024 + k0 + lchunk;
    ldsld16(ga, As + r0 * 32);
    ldsld16(ga + (size_t)16 * 1024, As + r0 * 32 + 512);
    ldsld16(gb, Bs + r0 * 32);
    ldsld16(gb + (size_t)16 * 1024, Bs + r0 * 32 + 512);
    __syncthreads();
    bf16x8 af[4], bw[4];
#pragma unroll
    for (int i = 0; i < 4; ++i) af[i] = *(const bf16x8*)(As + (wm + i * 16 + l16) * 32 + quad * 8);
#pragma unroll
    for (int j = 0; j < 4; ++j) bw[j] = *(const bf16x8*)(Bs + (wn + j * 16 + l16) * 32 + quad * 8);
#pragma unroll
    for (int i = 0; i < 4; ++i)
#pragma unroll
      for (int j = 0; j < 4; ++j) acc[i][j] = MFMA16(af[i], bw[j], acc[i][j]);
    __syncthreads();
  }
#pragma unroll
  for (int i = 0; i < 4; ++i)
#pragma unroll
    for (int j = 0; j < 4; ++j) {
      int gn = n0 + wn + j * 16 + l16;
      int h = gn >> 9, d = gn & 511;
      int gm0 = m0 + wm + i * 16 + quad * 4;
      int b = gm0 >> 11, t0 = gm0 & 2047;
      if (z == 2) {
        unsigned short pk[4];
#pragma unroll
        for (int r = 0; r < 4; ++r) pk[r] = f2bf(acc[i][j][r]);
        size_t off = ((size_t)((b * 8 + h) * 64 + (t0 >> 5))) * 16384 + (size_t)d * 32 + (t0 & 31);
        *(uint2*)(Vo + off) = *(uint2*)pk;   // packed 8B slab write
      } else {
        unsigned short* P = (z == 0) ? Qo : Ko;
        size_t base = ((size_t)((b * 8 + h) * 2048 + t0)) * 512 + d;
#pragma unroll
        for (int r = 0; r < 4; ++r) P[base + (size_t)r * 512] = f2bf(acc[i][j][r]);
      }
    }
}

// ---------------- RoPE (Q,K only; V slab untouched) ----------------
__global__ void rope_k(unsigned short* __restrict__ Q, unsigned short* __restrict__ K) {
  int idx = blockIdx.x * 256 + threadIdx.x;
  unsigned short* P = (idx & 8388608) ? K : Q;
  int r = idx & 8388607;
  int row = r >> 8;
  int i = r & 255;
  int t = row & 2047;
  size_t base = (size_t)row * 512;
  float x1 = bf2f(P[base + i]);
  float x2 = bf2f(P[base + i + 256]);
  float freq = expf(-(float)i * 0.03597789207803197f);
  float ang = (float)t * freq;
  float sv, cv;
  sincosf(ang, &sv, &cv);
  P[base + i]       = f2bf(x1 * cv - x2 * sv);
  P[base + i + 256] = f2bf(x1 * sv + x2 * cv);
}

// ---------------- flash attention v3 ----------------
// WG = 4 waves = 2 pairs; pair owns 16 q-rows, wave owns a 256-d half.
// QK: k-split across the pair, S summed via LDS. PV: d-split. K read direct from
// global (L2); V staged via global_load_lds from slab layout.
// grid (16 bh, jobs). q-tiles of 32 rows; qi>=32 split into 2 s-chunks.
__global__ __launch_bounds__(256, 3) void flash_attn(
    const unsigned short* __restrict__ Q, const unsigned short* __restrict__ K,
    const unsigned short* __restrict__ Vslab, unsigned short* __restrict__ attn,
    unsigned short* __restrict__ P1, float* __restrict__ ml1, float* __restrict__ ml2,
    int split) {
  __shared__ __align__(16) unsigned short Vs[512 * 32];  // 32KB, slab order [d][32]
  __shared__ __align__(16) unsigned short Ps[2 * 512];   // per-pair P[16][32] bf16
  __shared__ __align__(16) float Sred[2 * 2 * 512];      // [pair][half][col*16+row] f32
  const int tid = threadIdx.x;
  const int wave = tid >> 6, lane = tid & 63, quad = lane >> 4, l16 = lane & 15;
  const int pr = wave >> 1, hh = wave & 1;
  const int bh = blockIdx.x, b = bh >> 3, head = bh & 7;
  const int y = blockIdx.y;
  int qi, st0, stN, om;  // om: 0 direct, 1 chunk0->P1, 2 chunk1->attn unnormalized
  if (split) {
    if (y < 64) {
      qi = 63 - (y >> 1);
      int mid = (qi + 1) >> 1;
      if ((y & 1) == 0) { st0 = 0;   stN = mid;    om = 1; }
      else              { st0 = mid; stN = qi + 1; om = 2; }
    } else { qi = 95 - y; st0 = 0; stN = qi + 1; om = 0; }
  } else { qi = 63 - y; st0 = 0; stN = qi + 1; om = 0; }

  const size_t bhoff = (size_t)bh << 20;
  const unsigned short* Qp = Q + bhoff;
  const unsigned short* Kp = K + bhoff;
  const unsigned short* Vp = Vslab + bhoff;
  const int qb = qi * 32;

  // Q frags: own 256-d half, 8 k-steps (A-frag: m=l16, k=quad*8+j)
  bf16x8 qf[8];
  {
    const unsigned short* qrow = Qp + (size_t)(qb + pr * 16 + l16) * 512 + hh * 256 + quad * 8;
#pragma unroll
    for (int ks = 0; ks < 8; ++ks) qf[ks] = *(const bf16x8*)(qrow + ks * 32);
  }
  floatx4 o[16];
#pragma unroll
  for (int n = 0; n < 16; ++n) o[n] = (floatx4){0.f, 0.f, 0.f, 0.f};
  float m_[4], l_[4];
#pragma unroll
  for (int r = 0; r < 4; ++r) { m_[r] = -3.0e38f; l_[r] = 0.f; }

  // stage first V tile (async DMA; drained by the syncthreads before PV)
  {
    const unsigned short* g = Vp + (size_t)st0 * 16384 + (size_t)(wave * 8) * 512 + lane * 8;
    unsigned short* lp = Vs + wave * 8 * 512;
#pragma unroll
    for (int i = 0; i < 8; ++i) ldsld16(g + i * 512, lp + i * 512);
  }

  for (int st = st0; st < stN; ++st) {
    const int s0 = st * 32;
    // ---- QK partial over own 256 dims (K direct from global/L2) ----
    floatx4 sc0 = (floatx4){0.f, 0.f, 0.f, 0.f}, sc1 = sc0;
    const unsigned short* kbase = Kp + hh * 256 + quad * 8;
#pragma unroll
    for (int half = 0; half < 2; ++half) {
      bf16x8 kb[8];
#pragma unroll
      for (int q4 = 0; q4 < 4; ++q4) {
        int ks = half * 4 + q4;
        kb[q4 * 2]     = *(const bf16x8*)(kbase + (size_t)(s0 + l16) * 512 + ks * 32);
        kb[q4 * 2 + 1] = *(const bf16x8*)(kbase + (size_t)(s0 + 16 + l16) * 512 + ks * 32);
      }
#pragma unroll
      for (int q4 = 0; q4 < 4; ++q4) {
        sc0 = MFMA16(qf[half * 4 + q4], kb[q4 * 2], sc0);
        sc1 = MFMA16(qf[half * 4 + q4], kb[q4 * 2 + 1], sc1);
      }
    }
    // ---- cross-wave S reduction (col-major [col*16+row]) ----
    float* sw = Sred + (pr * 2 + hh) * 512;
    *(floatx4*)(sw + l16 * 16 + quad * 4) = sc0;
    *(floatx4*)(sw + (16 + l16) * 16 + quad * 4) = sc1;
    __syncthreads();  // barB
    {
      const float* srd = Sred + (pr * 2 + (1 - hh)) * 512;
      floatx4 r0 = *(const floatx4*)(srd + l16 * 16 + quad * 4);
      floatx4 r1 = *(const floatx4*)(srd + (16 + l16) * 16 + quad * 4);
#pragma unroll
      for (int r = 0; r < 4; ++r) { sc0[r] += r0[r]; sc1[r] += r1[r]; }
    }
    // ---- softmax (duplicated per pair — bit-identical in both waves) ----
    const float scale = 0.04419417382415922f;  // 1/sqrt(512)
    const int qrow0 = qb + pr * 16 + quad * 4;
    float pv0[4], pv1[4], mr[4];
#pragma unroll
    for (int r = 0; r < 4; ++r) {
      float a0 = sc0[r] * scale, a1 = sc1[r] * scale;
      if (s0 + l16 > qrow0 + r) a0 = -3.0e38f;
      if (s0 + 16 + l16 > qrow0 + r) a1 = -3.0e38f;
      pv0[r] = a0; pv1[r] = a1;
      mr[r] = fmaxf(a0, a1);
    }
#pragma unroll
    for (int off = 1; off < 16; off <<= 1)
#pragma unroll
      for (int r = 0; r < 4; ++r) mr[r] = fmaxf(mr[r], __shfl_xor(mr[r], off, 64));
    float alpha[4], rs[4];
#pragma unroll
    for (int r = 0; r < 4; ++r) {
      float mn = fmaxf(m_[r], mr[r]);
      alpha[r] = __expf(m_[r] - mn);
      m_[r] = mn;
      float p0 = __expf(pv0[r] - mn);
      float p1 = __expf(pv1[r] - mn);
      rs[r] = p0 + p1;
      // wave hh writes its 16-col block of P
      Ps[pr * 512 + (quad * 4 + r) * 32 + hh * 16 + l16] = f2bf(hh ? p1 : p0);
    }
#pragma unroll
    for (int off = 1; off < 16; off <<= 1)
#pragma unroll
      for (int r = 0; r < 4; ++r) rs[r] += __shfl_xor(rs[r], off, 64);
#pragma unroll
    for (int r = 0; r < 4; ++r) l_[r] = l_[r] * alpha[r] + rs[r];
    __syncthreads();  // barC: Ps visible, V DMA drained
    // ---- rescale O (skip when alpha==1 for all rows) ----
    if (__any(alpha[0] + alpha[1] + alpha[2] + alpha[3] < 4.0f)) {
#pragma unroll
      for (int n = 0; n < 16; ++n)
#pragma unroll
        for (int r = 0; r < 4; ++r) o[n][r] *= alpha[r];
    }
    // ---- PV over own 256-d half ----
    bf16x8 pf = *(const bf16x8*)(Ps + pr * 512 + l16 * 32 + quad * 8);
#pragma unroll
    for (int nt = 0; nt < 16; ++nt) {
      bf16x8 vf = *(const bf16x8*)(Vs + (size_t)(hh * 256 + nt * 16 + l16) * 32 + quad * 8);
      o[nt] = MFMA16(pf, vf, o[nt]);
    }
    __syncthreads();  // barD: Vs/Ps free for next tile
    if (st + 1 < stN) {
      const unsigned short* g = Vp + (size_t)(st + 1) * 16384 + (size_t)(wave * 8) * 512 + lane * 8;
      unsigned short* lp = Vs + wave * 8 * 512;
#pragma unroll
      for (int i = 0; i < 8; ++i) ldsld16(g + i * 512, lp + i * 512);
    }
  }
  // ---- outputs ----
  const int rbase = pr * 16 + quad * 4;  // +r
  int p1i = bh * 32 + (qi - 32);
  if (om == 1) {
    unsigned short* prow = P1 + ((size_t)p1i * 32 + rbase) * 512 + hh * 256 + l16;
#pragma unroll
    for (int nt = 0; nt < 16; ++nt)
#pragma unroll
      for (int r = 0; r < 4; ++r)
        prow[(size_t)r * 512 + nt * 16] = f2bf(o[nt][r]);   // unnormalized
  } else {
    unsigned short* arow =
        attn + ((size_t)(b * 2048 + qb + rbase)) * 4096 + head * 512 + hh * 256 + l16;
    if (om == 0) {
      float inv[4];
#pragma unroll
      for (int r = 0; r < 4; ++r) inv[r] = 1.0f / l_[r];
#pragma unroll
      for (int nt = 0; nt < 16; ++nt)
#pragma unroll
        for (int r = 0; r < 4; ++r)
          arow[(size_t)r * 4096 + nt * 16] = f2bf(o[nt][r] * inv[r]);
    } else {
#pragma unroll
      for (int nt = 0; nt < 16; ++nt)
#pragma unroll
        for (int r = 0; r < 4; ++r)
          arow[(size_t)r * 4096 + nt * 16] = f2bf(o[nt][r]);  // unnormalized
    }
  }
  if (om != 0 && hh == 0 && l16 == 0) {
    float* ml = (om == 1) ? ml1 : ml2;
#pragma unroll
    for (int r = 0; r < 4; ++r) {
      ml[(size_t)p1i * 64 + (rbase + r) * 2]     = m_[r];
      ml[(size_t)p1i * 64 + (rbase + r) * 2 + 1] = l_[r];
    }
  }
}

// ---------------- combine split partials (qi>=32) ----------------
__global__ void combine_k(const unsigned short* __restrict__ P1,
                          const float* __restrict__ ml1, const float* __restrict__ ml2,
                          unsigned short* __restrict__ attn) {
  const int p = blockIdx.x;  // [0,512)
  const int bh = p >> 5, qi = 32 + (p & 31), b = bh >> 3, head = bh & 7;
  const int tid = threadIdx.x;
#pragma unroll
  for (int it = 0; it < 8; ++it) {
    int idx = it * 256 + tid;        // 32 rows * 64 chunks
    int row = idx >> 6, c8 = (idx & 63) * 8;
    float m1 = ml1[(size_t)p * 64 + row * 2], l1 = ml1[(size_t)p * 64 + row * 2 + 1];
    float m2 = ml2[(size_t)p * 64 + row * 2], l2 = ml2[(size_t)p * 64 + row * 2 + 1];
    float M = fmaxf(m1, m2);
    float w1 = __expf(m1 - M), w2 = __expf(m2 - M);
    float inv = 1.0f / (l1 * w1 + l2 * w2);
    const unsigned short* o1 = P1 + ((size_t)p * 32 + row) * 512 + c8;
    unsigned short* ap = attn + ((size_t)(b * 2048 + qi * 32 + row)) * 4096 + head * 512 + c8;
    unsigned short res[8];
#pragma unroll
    for (int j = 0; j < 8; ++j)
      res[j] = f2bf((bf2f(o1[j]) * w1 + bf2f(ap[j]) * w2) * inv);
    *(bf16x8*)ap = *(bf16x8*)res;
  }
}

// ---------------- output projection: out += attn @ Wo^T (split-K, fp32 atomics) ----------------
__global__ __launch_bounds__(256) void out_gemm(
    const unsigned short* __restrict__ A, const unsigned short* __restrict__ W,
    float* __restrict__ C) {
  __shared__ __align__(16) unsigned short As[128 * 32];
  __shared__ __align__(16) unsigned short Bs[128 * 32];
  const int tid = threadIdx.x;
  const int wave = tid >> 6, lane = tid & 63, quad = lane >> 4, l16 = lane & 15;
  const int m0 = blockIdx.x * 128, n0 = blockIdx.y * 128;
  const int kb = blockIdx.z * 1024;
  const int wm = (wave >> 1) * 64, wn = (wave & 1) * 64;
  floatx4 acc[4][4];
#pragma unroll
  for (int i = 0; i < 4; ++i)
#pragma unroll
    for (int j = 0; j < 4; ++j) acc[i][j] = (floatx4){0.f, 0.f, 0.f, 0.f};
  const int r0 = wave * 32;
  const int lrow = lane >> 2, lchunk = (lane & 3) * 8;
  for (int k0 = kb; k0 < kb + 1024; k0 += 32) {
    const unsigned short* ga = A + (size_t)(m0 + r0 + lrow) * 4096 + k0 + lchunk;
    const unsigned short* gb = W + (size_t)(n0 + r0 + lrow) * 4096 + k0 + lchunk;
    ldsld16(ga, As + r0 * 32);
    ldsld16(ga + (size_t)16 * 4096, As + r0 * 32 + 512);
    ldsld16(gb, Bs + r0 * 32);
    ldsld16(gb + (size_t)16 * 4096, Bs + r0 * 32 + 512);
    __syncthreads();
    bf16x8 af[4], bw[4];
#pragma unroll
    for (int i = 0; i < 4; ++i) af[i] = *(const bf16x8*)(As + (wm + i * 16 + l16) * 32 + quad * 8);
#pragma unroll
    for (int j = 0; j < 4; ++j) bw[j] = *(const bf16x8*)(Bs + (wn + j * 16 + l16) * 32 + quad * 8);
#pragma unroll
    for (int i = 0; i < 4; ++i)
#pragma unroll
      for (int j = 0; j < 4; ++j) acc[i][j] = MFMA16(af[i], bw[j], acc[i][j]);
    __syncthreads();
  }
#pragma unroll
  for (int i = 0; i < 4; ++i)
#pragma unroll
    for (int j = 0; j < 4; ++j) {
      int gn = n0 + wn + j * 16 + l16;
#pragma unroll
      for (int r = 0; r < 4; ++r) {
        int gm = m0 + wm + i * 16 + quad * 4 + r;
        unsafeAtomicAdd(&C[(size_t)gm * 1024 + gn], acc[i][j][r]);
      }
    }
}

extern "C" void kernel_launch(void* const* d_in, const int* in_sizes, int n_in,
                              void* d_out, int out_size, void* d_ws, size_t ws_size,
                              hipStream_t stream) {
  const float* x  = (const float*)d_in[0];
  const float* Wq = (const float*)d_in[1];
  const float* Wk = (const float*)d_in[2];
  const float* Wv = (const float*)d_in[3];
  const float* Wo = (const float*)d_in[4];
  float* out = (float*)d_out;
  char* ws = (char*)d_ws;
  const size_t MB = 1048576;
  unsigned short* xb    = (unsigned short*)(ws + 0 * MB);
  unsigned short* wqb   = (unsigned short*)(ws + 8 * MB);
  unsigned short* wkb   = (unsigned short*)(ws + 16 * MB);
  unsigned short* wvb   = (unsigned short*)(ws + 24 * MB);
  unsigned short* wob   = (unsigned short*)(ws + 32 * MB);
  unsigned short* Qb    = (unsigned short*)(ws + 40 * MB);
  unsigned short* Kb    = (unsigned short*)(ws + 72 * MB);
  unsigned short* Vb    = (unsigned short*)(ws + 104 * MB);  // slab [BH][64][512][32]
  unsigned short* attnb = (unsigned short*)(ws + 0 * MB);    // reuse (dead post-qkv)
  unsigned short* P1    = (unsigned short*)(ws + 136 * MB);  // 16 MB (split mode)
  float* ml1            = (float*)(ws + 152 * MB);           // 128 KB
  float* ml2            = (float*)(ws + 152 * MB + 131072);  // 128 KB
  const int split = (ws_size >= (size_t)160 * MB) ? 1 : 0;

  hipMemsetAsync(d_out, 0, (size_t)4096 * 1024 * 4, stream);  // out_gemm accumulates

  cast5_k<<<dim3(4096, 5), 256, 0, stream>>>(x, Wq, Wk, Wv, Wo, xb, wqb, wkb, wvb, wob);
  qkv_gemm<<<dim3(32, 32, 3), 256, 0, stream>>>(xb, wqb, wkb, wvb, Qb, Kb, Vb);
  rope_k<<<65536, 256, 0, stream>>>(Qb, Kb);
  flash_attn<<<dim3(16, split ? 96 : 64), 256, 0, stream>>>(Qb, Kb, Vb, attnb, P1, ml1, ml2, split);
  if (split) combine_k<<<512, 256, 0, stream>>>(P1, ml1, ml2, attnb);
  out_gemm<<<dim3(32, 8, 4), 256, 0, stream>>>(attnb, wob, out);
}